// Round 5
// baseline (417.408 us; speedup 1.0000x reference)
//
#include <hip/hip_runtime.h>

typedef unsigned short u16;
typedef unsigned int u32;

typedef __attribute__((ext_vector_type(8)))  short bf16x8;
typedef __attribute__((ext_vector_type(4)))  float f32x4;

__device__ __forceinline__ float b2f(u16 u) {
    union { unsigned int i; float f; } v; v.i = ((unsigned int)u) << 16; return v.f;
}
__device__ __forceinline__ u16 f2b(float f) {
    union { float ff; unsigned int i; } v; v.ff = f;
    unsigned int x = v.i;
    return (u16)((x + 0x7fffu + ((x >> 16) & 1u)) >> 16);
}
__device__ __forceinline__ bool detect_bf16(const void* cosT) {
    // cos row 0 is all 1.0: fp32 word = 0x3F800000, bf16 pair = 0x3F803F80
    return ((*(const u32*)cosT) & 0xffffu) == 0x3f80u;
}
__device__ __forceinline__ float4 ld4(const void* p, size_t off, bool isbf) {
    if (isbf) {
        ushort4 v = *(const ushort4*)((const u16*)p + off);
        return make_float4(b2f(v.x), b2f(v.y), b2f(v.z), b2f(v.w));
    }
    return *(const float4*)((const float*)p + off);
}
__device__ __forceinline__ float lds1(const void* p, size_t off, bool isbf) {
    return isbf ? b2f(((const u16*)p)[off]) : ((const float*)p)[off];
}
// async 16B global -> LDS (dest = wave-uniform base + lane*16)
__device__ __forceinline__ void gll16(const void* g, void* l) {
    __builtin_amdgcn_global_load_lds(
        (const __attribute__((address_space(1))) u32*)g,
        (__attribute__((address_space(3))) u32*)l, 16, 0, 0);
}
// softcap + sliding-window mask. SCALING = 1/16, SOFTCAP = 50.
// masked -> -1e30, expf(-1e30) underflows to exactly 0.
__device__ __forceinline__ float capmask(float sdot, int i, int j) {
    float v = sdot * (0.0625f / 50.0f);
    v = fminf(fmaxf(v, -10.0f), 10.0f);
    float e = __expf(2.0f * v);
    float c = 50.0f * (e - 1.0f) / (e + 1.0f);
    bool allowed = (j <= i) && (j > i - 512);
    return allowed ? c : -1e30f;
}

// ---------------------------------------------------------------------------
// K0: prep = conv_hidden (blocks 0..2559) + weight transposes (2560..4159).
//   Hb[8192][640] bf16; WT[1536][640]; WoT[640][1024]
// ---------------------------------------------------------------------------
__global__ __launch_bounds__(256) void prep(
    const void* __restrict__ hidden,
    const void* __restrict__ Wq, const void* __restrict__ Wk,
    const void* __restrict__ Wv, const void* __restrict__ Wo,
    const void* __restrict__ cosT,
    u16* __restrict__ Hb, u16* __restrict__ WT, u16* __restrict__ WoT)
{
    const bool isbf = detect_bf16(cosT);
    __shared__ float T[32][33];
    int id = blockIdx.x;
    if (id < 2560) {
        size_t base = ((size_t)id * 256 + threadIdx.x) * 8;
        if (isbf) {
            *(uint4*)(Hb + base) = *(const uint4*)((const u16*)hidden + base);
        } else {
            float4 a = ld4(hidden, base, false);
            float4 b = ld4(hidden, base + 4, false);
            uint4 o;
            o.x = (u32)f2b(a.x) | ((u32)f2b(a.y) << 16);
            o.y = (u32)f2b(a.z) | ((u32)f2b(a.w) << 16);
            o.z = (u32)f2b(b.x) | ((u32)f2b(b.y) << 16);
            o.w = (u32)f2b(b.z) | ((u32)f2b(b.w) << 16);
            *(uint4*)(Hb + base) = o;
        }
        return;
    }
    id -= 2560;
    const int tx = threadIdx.x & 31, ty = threadIdx.x >> 5;
    if (id < 960) {
        const int n0 = (id % 48) * 32, k0 = (id / 48) * 32;
        const void* src; int ldw, nof;
        if (n0 < 1024)      { src = Wq; ldw = 1024; nof = n0; }
        else if (n0 < 1280) { src = Wk; ldw = 256;  nof = n0 - 1024; }
        else                { src = Wv; ldw = 256;  nof = n0 - 1280; }
#pragma unroll
        for (int j = 0; j < 4; j++)
            T[ty + 8 * j][tx] = lds1(src, (size_t)(k0 + ty + 8 * j) * ldw + nof + tx, isbf);
        __syncthreads();
#pragma unroll
        for (int j = 0; j < 4; j++)
            WT[(size_t)(n0 + ty + 8 * j) * 640 + k0 + tx] = f2b(T[tx][ty + 8 * j]);
    } else {
        id -= 960;
        const int k0 = (id & 31) * 32, n0 = (id >> 5) * 32;
#pragma unroll
        for (int j = 0; j < 4; j++)
            T[ty + 8 * j][tx] = lds1(Wo, (size_t)(k0 + ty + 8 * j) * 640 + n0 + tx, isbf);
        __syncthreads();
#pragma unroll
        for (int j = 0; j < 4; j++)
            WoT[(size_t)(n0 + ty + 8 * j) * 1024 + k0 + tx] = f2b(T[tx][ty + 8 * j]);
    }
}

// ---------------------------------------------------------------------------
// K1: QKV GEMM (MFMA bf16 + global_load_lds staging).
// 128x128 tile, BK=32, 4 waves (2x2 of 64x64), 16x16x32 MFMA.
// V written transposed to Vtg[b][256][4096].
// ---------------------------------------------------------------------------
__global__ __launch_bounds__(256) void qkv_gemm(
    const u16* __restrict__ Hb, const u16* __restrict__ WT,
    u16* __restrict__ Qb, u16* __restrict__ Kb, u16* __restrict__ Vtg)
{
    const int n0 = blockIdx.x * 128, m0 = blockIdx.y * 128;
    const int t = threadIdx.x, w = t >> 6, lane = t & 63;
    const int l15 = lane & 15, quad = lane >> 4;
    const int wm = (w & 1) * 64, wn = (w >> 1) * 64;

    __shared__ __align__(16) u16 Ah[128][32];
    __shared__ __align__(16) u16 Bh[128][32];

    f32x4 acc[4][4];
#pragma unroll
    for (int i = 0; i < 4; i++)
#pragma unroll
        for (int j = 0; j < 4; j++) acc[i][j] = (f32x4)0.0f;

    for (int kb = 0; kb < 640; kb += 32) {
        __syncthreads();
#pragma unroll
        for (int i = 0; i < 2; i++) {
            int ci = t + 256 * i, m = ci >> 2, c = ci & 3;
            gll16(Hb + (size_t)(m0 + m) * 640 + kb + c * 8, (char*)&Ah[0][0] + ci * 16);
            gll16(WT + (size_t)(n0 + m) * 640 + kb + c * 8, (char*)&Bh[0][0] + ci * 16);
        }
        __syncthreads();
        bf16x8 af[4], bfr[4];
#pragma unroll
        for (int mi = 0; mi < 4; mi++)
            af[mi] = *(const bf16x8*)&Ah[wm + mi * 16 + l15][quad * 8];
#pragma unroll
        for (int ni = 0; ni < 4; ni++)
            bfr[ni] = *(const bf16x8*)&Bh[wn + ni * 16 + l15][quad * 8];
#pragma unroll
        for (int mi = 0; mi < 4; mi++)
#pragma unroll
            for (int ni = 0; ni < 4; ni++)
                acc[mi][ni] = __builtin_amdgcn_mfma_f32_16x16x32_bf16(
                    af[mi], bfr[ni], acc[mi][ni], 0, 0, 0);
    }

    const int bb = m0 >> 12, sblk = m0 & 4095;
#pragma unroll
    for (int mi = 0; mi < 4; mi++)
#pragma unroll
        for (int ni = 0; ni < 4; ni++) {
            int rowb = m0 + wm + mi * 16 + quad * 4;
            int col  = n0 + wn + ni * 16 + l15;
            if (n0 < 1024) {
#pragma unroll
                for (int r = 0; r < 4; r++)
                    Qb[(size_t)(rowb + r) * 1024 + col] = f2b(acc[mi][ni][r]);
            } else if (n0 < 1280) {
#pragma unroll
                for (int r = 0; r < 4; r++)
                    Kb[(size_t)(rowb + r) * 256 + (col - 1024)] = f2b(acc[mi][ni][r]);
            } else {
                int vd = col - 1280;
                int sb = sblk + wm + mi * 16 + quad * 4;
                ushort4 vv = make_ushort4(f2b(acc[mi][ni][0]), f2b(acc[mi][ni][1]),
                                          f2b(acc[mi][ni][2]), f2b(acc[mi][ni][3]));
                *(ushort4*)(Vtg + (size_t)bb * 1048576 + (size_t)vd * 4096 + sb) = vv;
            }
        }
}

// ---------------------------------------------------------------------------
// K2: RMS-norm + RoPE for K only (Q is fused into attn). One wave per row.
// ---------------------------------------------------------------------------
__global__ __launch_bounds__(64) void k_norm_rope(
    u16* __restrict__ Kb,
    const void* __restrict__ cosT, const void* __restrict__ sinT,
    const void* __restrict__ kw)
{
    const bool isbf = detect_bf16(cosT);
    const int row = blockIdx.x, s = row & 4095;
    const int lane = threadIdx.x, d0 = lane * 4;

    u16* p = Kb + (size_t)row * 256 + d0;
    ushort4 xv = *(const ushort4*)p;
    float x0 = b2f(xv.x), x1 = b2f(xv.y), x2 = b2f(xv.z), x3 = b2f(xv.w);
    float ssum = x0 * x0 + x1 * x1 + x2 * x2 + x3 * x3;
#pragma unroll
    for (int off = 32; off > 0; off >>= 1) ssum += __shfl_xor(ssum, off, 64);
    float rs = rsqrtf(ssum * (1.0f / 256.0f) + 1e-6f);

    float4 wv = ld4(kw, d0, isbf);
    float n0 = x0 * rs * (1.0f + wv.x);
    float n1 = x1 * rs * (1.0f + wv.y);
    float n2 = x2 * rs * (1.0f + wv.z);
    float n3 = x3 * rs * (1.0f + wv.w);

    float o0 = __shfl_xor(n0, 32, 64);
    float o1 = __shfl_xor(n1, 32, 64);
    float o2 = __shfl_xor(n2, 32, 64);
    float o3 = __shfl_xor(n3, 32, 64);
    float sgn = (lane < 32) ? -1.0f : 1.0f;

    float4 cv = ld4(cosT, (size_t)s * 256 + d0, isbf);
    float4 sv = ld4(sinT, (size_t)s * 256 + d0, isbf);
    *(ushort4*)p = make_ushort4(
        f2b(n0 * cv.x + sgn * o0 * sv.x), f2b(n1 * cv.y + sgn * o1 * sv.y),
        f2b(n2 * cv.z + sgn * o2 * sv.z), f2b(n3 * cv.w + sgn * o3 * sv.w));
}

// ---------------------------------------------------------------------------
// K3: sliding-window flash attention, 16x16x32 MFMA.
// Block = 4 waves = 4 heads x same 16 queries. Q-side RMS-norm + RoPE fused
// into the fragment load (lane: q=q0+l15, d=quad*8+s*32+j; RoPE partner
// d+/-128 = fragment s+/-4, same lane; 256-d sum = shfl_xor 16,32).
// K/V register-prefetched across the barrier. Fixed-max softmax.
// ---------------------------------------------------------------------------
__global__ __launch_bounds__(256, 3) void attn_mfma(
    const u16* __restrict__ Qb, const u16* __restrict__ Kb,
    const u16* __restrict__ Vtg,
    const void* __restrict__ cosT, const void* __restrict__ sinT,
    const void* __restrict__ qw, u16* __restrict__ AO)
{
    const bool isbf = detect_bf16(cosT);
    const int q0 = blockIdx.x * 16;
    const int b  = blockIdx.y;
    const int t = threadIdx.x, h = t >> 6, lane = t & 63;
    const int l15 = lane & 15, quad = lane >> 4;

    __shared__ __align__(16) u16 Ks[32][264];
    __shared__ __align__(16) u16 Vt[256][40];
    __shared__ __align__(16) u16 Pr[4][16][40];
    __shared__ float l_s[4][16];

    // ---- Q fragments with fused RMS-norm + RoPE
    bf16x8 qf[8];
    {
        const u16* qp = Qb + ((size_t)(b * 4096 + q0 + l15)) * 1024 + h * 256 + quad * 8;
#pragma unroll
        for (int s = 0; s < 8; s++) qf[s] = *(const bf16x8*)(qp + s * 32);
        float ss = 0.f;
#pragma unroll
        for (int s = 0; s < 8; s++)
#pragma unroll
            for (int j = 0; j < 8; j++) { float v = b2f((u16)qf[s][j]); ss += v * v; }
        ss += __shfl_xor(ss, 16, 64);
        ss += __shfl_xor(ss, 32, 64);
        const float rs = rsqrtf(ss * (1.0f / 256.0f) + 1e-6f);
        const size_t crow = (size_t)(q0 + l15) * 256;
#pragma unroll
        for (int sp = 0; sp < 4; sp++) {
            const int da = quad * 8 + sp * 32, db = da + 128;
            float4 w0 = ld4(qw, da, isbf),        w1 = ld4(qw, da + 4, isbf);
            float4 u0 = ld4(qw, db, isbf),        u1 = ld4(qw, db + 4, isbf);
            float4 ca0 = ld4(cosT, crow + da, isbf), ca1 = ld4(cosT, crow + da + 4, isbf);
            float4 cb0 = ld4(cosT, crow + db, isbf), cb1 = ld4(cosT, crow + db + 4, isbf);
            float4 sa0 = ld4(sinT, crow + da, isbf), sa1 = ld4(sinT, crow + da + 4, isbf);
            float4 sb0 = ld4(sinT, crow + db, isbf), sb1 = ld4(sinT, crow + db + 4, isbf);
            float wa[8] = {w0.x,w0.y,w0.z,w0.w,w1.x,w1.y,w1.z,w1.w};
            float wb[8] = {u0.x,u0.y,u0.z,u0.w,u1.x,u1.y,u1.z,u1.w};
            float ca[8] = {ca0.x,ca0.y,ca0.z,ca0.w,ca1.x,ca1.y,ca1.z,ca1.w};
            float cb[8] = {cb0.x,cb0.y,cb0.z,cb0.w,cb1.x,cb1.y,cb1.z,cb1.w};
            float sa[8] = {sa0.x,sa0.y,sa0.z,sa0.w,sa1.x,sa1.y,sa1.z,sa1.w};
            float sb[8] = {sb0.x,sb0.y,sb0.z,sb0.w,sb1.x,sb1.y,sb1.z,sb1.w};
            bf16x8 outa, outb;
#pragma unroll
            for (int j = 0; j < 8; j++) {
                float na = b2f((u16)qf[sp][j])     * rs * (1.0f + wa[j]);
                float nb = b2f((u16)qf[sp + 4][j]) * rs * (1.0f + wb[j]);
                outa[j] = (short)f2b(na * ca[j] - nb * sa[j]);
                outb[j] = (short)f2b(nb * cb[j] + na * sb[j]);
            }
            qf[sp] = outa; qf[sp + 4] = outb;
        }
    }

    f32x4 o[16];
#pragma unroll
    for (int i = 0; i < 16; i++) o[i] = (f32x4)0.0f;
    float lp[4] = {0.f, 0.f, 0.f, 0.f};

    const int lo = q0 - 511;
    const int jb0 = lo > 0 ? (lo >> 5) << 5 : 0;
    const int jb1 = (q0 + 15) & ~31;

    const u16* kbase = Kb + (size_t)b * 4096 * 256;
    const u16* vbase = Vtg + (size_t)b * 1048576;

    uint4 kreg[4], vreg[4];
#pragma unroll
    for (int i = 0; i < 4; i++) {
        int ci = t + 256 * i;
        kreg[i] = *(const uint4*)(kbase + (size_t)(jb0 + (ci >> 5)) * 256 + (ci & 31) * 8);
        vreg[i] = *(const uint4*)(vbase + (size_t)(ci >> 2) * 4096 + jb0 + (ci & 3) * 8);
    }

    for (int jb = jb0; jb <= jb1; jb += 32) {
        __syncthreads();
#pragma unroll
        for (int i = 0; i < 4; i++) {
            int ci = t + 256 * i;
            *(uint4*)&Ks[ci >> 5][(ci & 31) * 8] = kreg[i];
            *(uint4*)&Vt[ci >> 2][(ci & 3) * 8]  = vreg[i];
        }
        __syncthreads();
        if (jb + 32 <= jb1) {
            const int jn = jb + 32;
#pragma unroll
            for (int i = 0; i < 4; i++) {
                int ci = t + 256 * i;
                kreg[i] = *(const uint4*)(kbase + (size_t)(jn + (ci >> 5)) * 256 + (ci & 31) * 8);
                vreg[i] = *(const uint4*)(vbase + (size_t)(ci >> 2) * 4096 + jn + (ci & 3) * 8);
            }
        }

        // ---- S = Q K^T : 16 queries x 32 keys
        f32x4 s0 = (f32x4)0.0f, s1 = (f32x4)0.0f;
#pragma unroll
        for (int ds = 0; ds < 8; ds++) {
            bf16x8 kf0 = *(const bf16x8*)&Ks[l15][ds * 32 + quad * 8];
            bf16x8 kf1 = *(const bf16x8*)&Ks[16 + l15][ds * 32 + quad * 8];
            s0 = __builtin_amdgcn_mfma_f32_16x16x32_bf16(qf[ds], kf0, s0, 0, 0, 0);
            s1 = __builtin_amdgcn_mfma_f32_16x16x32_bf16(qf[ds], kf1, s1, 0, 0, 0);
        }
        // ---- softcap + mask + exp (fixed max), P -> LDS
        const int j0 = jb + l15;
#pragma unroll
        for (int r = 0; r < 4; r++) {
            int qi = q0 + quad * 4 + r;
            float p0 = __expf(capmask(s0[r], qi, j0));
            float p1 = __expf(capmask(s1[r], qi, j0 + 16));
            u16 pb0 = f2b(p0), pb1 = f2b(p1);
            Pr[h][quad * 4 + r][l15]      = pb0;
            Pr[h][quad * 4 + r][16 + l15] = pb1;
            lp[r] += b2f(pb0) + b2f(pb1);
        }
        __threadfence_block();
        // ---- O^T += V^T P^T
#pragma unroll
        for (int mt = 0; mt < 16; mt++) {
            bf16x8 vf = *(const bf16x8*)&Vt[mt * 16 + l15][quad * 8];
            bf16x8 pf = *(const bf16x8*)&Pr[h][l15][quad * 8];
            o[mt] = __builtin_amdgcn_mfma_f32_16x16x32_bf16(vf, pf, o[mt], 0, 0, 0);
        }
    }

    // ---- l reduction across the 16 key-lanes
#pragma unroll
    for (int r = 0; r < 4; r++) {
        float v = lp[r];
        v += __shfl_xor(v, 1, 64); v += __shfl_xor(v, 2, 64);
        v += __shfl_xor(v, 4, 64); v += __shfl_xor(v, 8, 64);
        lp[r] = v;
    }
    if (l15 == 0) {
#pragma unroll
        for (int r = 0; r < 4; r++) l_s[h][quad * 4 + r] = lp[r];
    }
    __threadfence_block();
    __syncthreads();
    const float inv = 1.0f / l_s[h][l15];

    u16* aop = AO + ((size_t)(b * 4096 + q0 + l15)) * 1024 + h * 256 + quad * 4;
#pragma unroll
    for (int mt = 0; mt < 16; mt++) {
        *(ushort4*)(aop + mt * 16) = make_ushort4(
            f2b(o[mt][0] * inv), f2b(o[mt][1] * inv),
            f2b(o[mt][2] * inv), f2b(o[mt][3] * inv));
    }
}

// ---------------------------------------------------------------------------
// K4: output projection (MFMA bf16 + global_load_lds staging).
// BM=128, BN=64 -> grid (10,64)=640 blocks (2.5/CU). 4 waves 2x2 of 64x32.
// ---------------------------------------------------------------------------
__global__ __launch_bounds__(256) void out_gemm(
    const u16* __restrict__ AO, const u16* __restrict__ WoT,
    const void* __restrict__ cosT, void* __restrict__ outp)
{
    const bool isbf = detect_bf16(cosT);
    const int n0 = blockIdx.x * 64, m0 = blockIdx.y * 128;
    const int t = threadIdx.x, w = t >> 6, lane = t & 63;
    const int l15 = lane & 15, quad = lane >> 4;
    const int wm = (w & 1) * 64, wn = (w >> 1) * 32;

    __shared__ __align__(16) u16 Ah[128][32];
    __shared__ __align__(16) u16 Bh[64][32];

    f32x4 acc[4][2];
#pragma unroll
    for (int i = 0; i < 4; i++)
#pragma unroll
        for (int j = 0; j < 2; j++) acc[i][j] = (f32x4)0.0f;

    for (int kb = 0; kb < 1024; kb += 32) {
        __syncthreads();
#pragma unroll
        for (int i = 0; i < 2; i++) {
            int ci = t + 256 * i, m = ci >> 2, c = ci & 3;
            gll16(AO + (size_t)(m0 + m) * 1024 + kb + c * 8, (char*)&Ah[0][0] + ci * 16);
        }
        {
            int m = t >> 2, c = t & 3;
            gll16(WoT + (size_t)(n0 + m) * 1024 + kb + c * 8, (char*)&Bh[0][0] + t * 16);
        }
        __syncthreads();
        bf16x8 af[4], bfr[2];
#pragma unroll
        for (int mi = 0; mi < 4; mi++)
            af[mi] = *(const bf16x8*)&Ah[wm + mi * 16 + l15][quad * 8];
#pragma unroll
        for (int ni = 0; ni < 2; ni++)
            bfr[ni] = *(const bf16x8*)&Bh[wn + ni * 16 + l15][quad * 8];
#pragma unroll
        for (int mi = 0; mi < 4; mi++)
#pragma unroll
            for (int ni = 0; ni < 2; ni++)
                acc[mi][ni] = __builtin_amdgcn_mfma_f32_16x16x32_bf16(
                    af[mi], bfr[ni], acc[mi][ni], 0, 0, 0);
    }

#pragma unroll
    for (int mi = 0; mi < 4; mi++)
#pragma unroll
        for (int ni = 0; ni < 2; ni++) {
            int rowb = m0 + wm + mi * 16 + quad * 4;
            int col  = n0 + wn + ni * 16 + l15;
            if (isbf) {
#pragma unroll
                for (int r = 0; r < 4; r++)
                    ((u16*)outp)[(size_t)(rowb + r) * 640 + col] = f2b(acc[mi][ni][r]);
            } else {
#pragma unroll
                for (int r = 0; r < 4; r++)
                    ((float*)outp)[(size_t)(rowb + r) * 640 + col] = acc[mi][ni][r];
            }
        }
}

// ---------------------------------------------------------------------------
// Launch. Inputs: 0 hidden, 1 cos, 2 sin, 3 mask(UNUSED), 4 Wq, 5 Wk, 6 Wv,
// 7 Wo, 8 q_norm_w, 9 k_norm_w. Workspace (43.3 MB, AO overlays Hb+WT):
//   [0, 16.78M): Hb(10.49M) + WT(1.97M)  -- dead after GEMMs; AO reuses @0
//   [16.78M): WoT 1.31M | Qb 16.78M | Kb 4.19M | Vt_g 4.19M
// ---------------------------------------------------------------------------
extern "C" void kernel_launch(void* const* d_in, const int* in_sizes, int n_in,
                              void* d_out, int out_size, void* d_ws, size_t ws_size,
                              hipStream_t stream) {
    const void* hidden = d_in[0];
    const void* cosT   = d_in[1];
    const void* sinT   = d_in[2];
    const void* Wq     = d_in[4];
    const void* Wk     = d_in[5];
    const void* Wv     = d_in[6];
    const void* Wo     = d_in[7];
    const void* qw     = d_in[8];
    const void* kw     = d_in[9];

    char* ws = (char*)d_ws;
    u16* Hb  = (u16*)ws;                            // 8192*640
    u16* WT  = (u16*)(ws + 10485760);               // 1536*640
    u16* AO  = (u16*)ws;                            // 8192*1024 (overlays Hb/WT)
    u16* WoT = (u16*)(ws + 16777216);               // 640*1024
    u16* Qb  = (u16*)(ws + 18087936);               // 8192*1024
    u16* Kb  = (u16*)(ws + 34865152);               // 8192*256
    u16* Vtg = (u16*)(ws + 39059456);               // 2*256*4096

    prep<<<dim3(4160), 256, 0, stream>>>(hidden, Wq, Wk, Wv, Wo, cosT, Hb, WT, WoT);
    qkv_gemm<<<dim3(12, 64), 256, 0, stream>>>(Hb, WT, Qb, Kb, Vtg);
    k_norm_rope<<<dim3(8192), 64, 0, stream>>>(Kb, cosT, sinT, kw);
    attn_mfma<<<dim3(256, 2), 256, 0, stream>>>(Qb, Kb, Vtg, cosT, sinT, qw, AO);
    out_gemm<<<dim3(10, 64), 256, 0, stream>>>(AO, WoT, cosT, d_out);
}

// Round 6
// 400.814 us; speedup vs baseline: 1.0414x; 1.0414x over previous
//
#include <hip/hip_runtime.h>

typedef unsigned short u16;
typedef unsigned int u32;

typedef __attribute__((ext_vector_type(8)))  short bf16x8;
typedef __attribute__((ext_vector_type(4)))  float f32x4;

__device__ __forceinline__ float b2f(u16 u) {
    union { unsigned int i; float f; } v; v.i = ((unsigned int)u) << 16; return v.f;
}
__device__ __forceinline__ u16 f2b(float f) {
    union { float ff; unsigned int i; } v; v.ff = f;
    unsigned int x = v.i;
    return (u16)((x + 0x7fffu + ((x >> 16) & 1u)) >> 16);
}
__device__ __forceinline__ bool detect_bf16(const void* cosT) {
    // cos row 0 is all 1.0: fp32 word = 0x3F800000, bf16 pair = 0x3F803F80
    return ((*(const u32*)cosT) & 0xffffu) == 0x3f80u;
}
__device__ __forceinline__ float4 ld4(const void* p, size_t off, bool isbf) {
    if (isbf) {
        ushort4 v = *(const ushort4*)((const u16*)p + off);
        return make_float4(b2f(v.x), b2f(v.y), b2f(v.z), b2f(v.w));
    }
    return *(const float4*)((const float*)p + off);
}
__device__ __forceinline__ float lds1(const void* p, size_t off, bool isbf) {
    return isbf ? b2f(((const u16*)p)[off]) : ((const float*)p)[off];
}
// async 16B global -> LDS (dest = wave-uniform base + lane*16)
__device__ __forceinline__ void gll16(const void* g, void* l) {
    __builtin_amdgcn_global_load_lds(
        (const __attribute__((address_space(1))) u32*)g,
        (__attribute__((address_space(3))) u32*)l, 16, 0, 0);
}
// softcap + sliding-window mask. SCALING = 1/16, SOFTCAP = 50.
// masked -> -1e30, expf(-1e30) underflows to exactly 0.
__device__ __forceinline__ float capmask(float sdot, int i, int j) {
    float v = sdot * (0.0625f / 50.0f);
    v = fminf(fmaxf(v, -10.0f), 10.0f);
    float e = __expf(2.0f * v);
    float c = 50.0f * (e - 1.0f) / (e + 1.0f);
    bool allowed = (j <= i) && (j > i - 512);
    return allowed ? c : -1e30f;
}

// ---------------------------------------------------------------------------
// K0: prep = conv_hidden (blocks 0..2559) + weight transposes (2560..4159).
//   Hb[8192][640] bf16; WT[1536][640]; WoT[640][1024]
// ---------------------------------------------------------------------------
__global__ __launch_bounds__(256) void prep(
    const void* __restrict__ hidden,
    const void* __restrict__ Wq, const void* __restrict__ Wk,
    const void* __restrict__ Wv, const void* __restrict__ Wo,
    const void* __restrict__ cosT,
    u16* __restrict__ Hb, u16* __restrict__ WT, u16* __restrict__ WoT)
{
    const bool isbf = detect_bf16(cosT);
    __shared__ float T[32][33];
    int id = blockIdx.x;
    if (id < 2560) {
        size_t base = ((size_t)id * 256 + threadIdx.x) * 8;
        if (isbf) {
            *(uint4*)(Hb + base) = *(const uint4*)((const u16*)hidden + base);
        } else {
            float4 a = ld4(hidden, base, false);
            float4 b = ld4(hidden, base + 4, false);
            uint4 o;
            o.x = (u32)f2b(a.x) | ((u32)f2b(a.y) << 16);
            o.y = (u32)f2b(a.z) | ((u32)f2b(a.w) << 16);
            o.z = (u32)f2b(b.x) | ((u32)f2b(b.y) << 16);
            o.w = (u32)f2b(b.z) | ((u32)f2b(b.w) << 16);
            *(uint4*)(Hb + base) = o;
        }
        return;
    }
    id -= 2560;
    const int tx = threadIdx.x & 31, ty = threadIdx.x >> 5;
    if (id < 960) {
        const int n0 = (id % 48) * 32, k0 = (id / 48) * 32;
        const void* src; int ldw, nof;
        if (n0 < 1024)      { src = Wq; ldw = 1024; nof = n0; }
        else if (n0 < 1280) { src = Wk; ldw = 256;  nof = n0 - 1024; }
        else                { src = Wv; ldw = 256;  nof = n0 - 1280; }
#pragma unroll
        for (int j = 0; j < 4; j++)
            T[ty + 8 * j][tx] = lds1(src, (size_t)(k0 + ty + 8 * j) * ldw + nof + tx, isbf);
        __syncthreads();
#pragma unroll
        for (int j = 0; j < 4; j++)
            WT[(size_t)(n0 + ty + 8 * j) * 640 + k0 + tx] = f2b(T[tx][ty + 8 * j]);
    } else {
        id -= 960;
        const int k0 = (id & 31) * 32, n0 = (id >> 5) * 32;
#pragma unroll
        for (int j = 0; j < 4; j++)
            T[ty + 8 * j][tx] = lds1(Wo, (size_t)(k0 + ty + 8 * j) * 640 + n0 + tx, isbf);
        __syncthreads();
#pragma unroll
        for (int j = 0; j < 4; j++)
            WoT[(size_t)(n0 + ty + 8 * j) * 1024 + k0 + tx] = f2b(T[tx][ty + 8 * j]);
    }
}

// ---------------------------------------------------------------------------
// K1: QKV GEMM (MFMA bf16 + global_load_lds staging).
// 128x128 tile, BK=32, 4 waves (2x2 of 64x64), 16x16x32 MFMA.
// Epilogue: Q/K via LDS tile -> coalesced uint4 stores; V direct transposed.
// ---------------------------------------------------------------------------
__global__ __launch_bounds__(256) void qkv_gemm(
    const u16* __restrict__ Hb, const u16* __restrict__ WT,
    u16* __restrict__ Qb, u16* __restrict__ Kb, u16* __restrict__ Vtg)
{
    const int n0 = blockIdx.x * 128, m0 = blockIdx.y * 128;
    const int t = threadIdx.x, w = t >> 6, lane = t & 63;
    const int l15 = lane & 15, quad = lane >> 4;
    const int wm = (w & 1) * 64, wn = (w >> 1) * 64;

    __shared__ __align__(16) u16 Ah[128][32];
    __shared__ __align__(16) u16 Bh[128][32];
    __shared__ __align__(16) u16 Sc[128][132];

    f32x4 acc[4][4];
#pragma unroll
    for (int i = 0; i < 4; i++)
#pragma unroll
        for (int j = 0; j < 4; j++) acc[i][j] = (f32x4)0.0f;

    for (int kb = 0; kb < 640; kb += 32) {
        __syncthreads();
#pragma unroll
        for (int i = 0; i < 2; i++) {
            int ci = t + 256 * i, m = ci >> 2, c = ci & 3;
            gll16(Hb + (size_t)(m0 + m) * 640 + kb + c * 8, (char*)&Ah[0][0] + ci * 16);
            gll16(WT + (size_t)(n0 + m) * 640 + kb + c * 8, (char*)&Bh[0][0] + ci * 16);
        }
        __syncthreads();
        bf16x8 af[4], bfr[4];
#pragma unroll
        for (int mi = 0; mi < 4; mi++)
            af[mi] = *(const bf16x8*)&Ah[wm + mi * 16 + l15][quad * 8];
#pragma unroll
        for (int ni = 0; ni < 4; ni++)
            bfr[ni] = *(const bf16x8*)&Bh[wn + ni * 16 + l15][quad * 8];
#pragma unroll
        for (int mi = 0; mi < 4; mi++)
#pragma unroll
            for (int ni = 0; ni < 4; ni++)
                acc[mi][ni] = __builtin_amdgcn_mfma_f32_16x16x32_bf16(
                    af[mi], bfr[ni], acc[mi][ni], 0, 0, 0);
    }

    if (n0 >= 1280) {
        // V region: direct transposed store (already vectorized)
        const int bb = m0 >> 12, sblk = m0 & 4095;
#pragma unroll
        for (int mi = 0; mi < 4; mi++)
#pragma unroll
            for (int ni = 0; ni < 4; ni++) {
                int vd = n0 + wn + ni * 16 + l15 - 1280;
                int sb = sblk + wm + mi * 16 + quad * 4;
                ushort4 vv = make_ushort4(f2b(acc[mi][ni][0]), f2b(acc[mi][ni][1]),
                                          f2b(acc[mi][ni][2]), f2b(acc[mi][ni][3]));
                *(ushort4*)(Vtg + (size_t)bb * 1048576 + (size_t)vd * 4096 + sb) = vv;
            }
        return;
    }

    __syncthreads();   // LDS tiles dead; reuse Sc
#pragma unroll
    for (int mi = 0; mi < 4; mi++)
#pragma unroll
        for (int ni = 0; ni < 4; ni++)
#pragma unroll
            for (int r = 0; r < 4; r++)
                Sc[wm + mi * 16 + quad * 4 + r][wn + ni * 16 + l15] = f2b(acc[mi][ni][r]);
    __syncthreads();

    u16* dst; int ldo, coff;
    if (n0 < 1024) { dst = Qb; ldo = 1024; coff = n0; }
    else           { dst = Kb; ldo = 256;  coff = n0 - 1024; }
#pragma unroll
    for (int i = 0; i < 8; i++) {
        int idx = t + 256 * i, r = idx >> 4, c = idx & 15;
        *(uint4*)(dst + (size_t)(m0 + r) * ldo + coff + c * 8) = *(const uint4*)&Sc[r][c * 8];
    }
}

// ---------------------------------------------------------------------------
// K2: fused RMS-norm + RoPE in place on Qb (4 heads) and Kb (1 head).
// ---------------------------------------------------------------------------
__global__ __launch_bounds__(320) void norm_rope(
    u16* __restrict__ Qb, u16* __restrict__ Kb,
    const void* __restrict__ cosT, const void* __restrict__ sinT,
    const void* __restrict__ qw, const void* __restrict__ kw)
{
    const bool isbf = detect_bf16(cosT);
    const int row = blockIdx.x, s = row & 4095;
    const int g = threadIdx.x >> 6, lane = threadIdx.x & 63, d0 = lane * 4;

    u16* p; const void* w;
    if (g < 4) { p = Qb + (size_t)row * 1024 + g * 256 + d0; w = qw; }
    else       { p = Kb + (size_t)row * 256 + d0;            w = kw; }

    ushort4 xv = *(const ushort4*)p;
    float x0 = b2f(xv.x), x1 = b2f(xv.y), x2 = b2f(xv.z), x3 = b2f(xv.w);
    float ssum = x0 * x0 + x1 * x1 + x2 * x2 + x3 * x3;
#pragma unroll
    for (int off = 32; off > 0; off >>= 1) ssum += __shfl_xor(ssum, off, 64);
    float rs = rsqrtf(ssum * (1.0f / 256.0f) + 1e-6f);

    float4 wv = ld4(w, d0, isbf);
    float n0 = x0 * rs * (1.0f + wv.x);
    float n1 = x1 * rs * (1.0f + wv.y);
    float n2 = x2 * rs * (1.0f + wv.z);
    float n3 = x3 * rs * (1.0f + wv.w);

    float o0 = __shfl_xor(n0, 32, 64);
    float o1 = __shfl_xor(n1, 32, 64);
    float o2 = __shfl_xor(n2, 32, 64);
    float o3 = __shfl_xor(n3, 32, 64);
    float sgn = (lane < 32) ? -1.0f : 1.0f;

    float4 cv = ld4(cosT, (size_t)s * 256 + d0, isbf);
    float4 sv = ld4(sinT, (size_t)s * 256 + d0, isbf);
    *(ushort4*)p = make_ushort4(
        f2b(n0 * cv.x + sgn * o0 * sv.x), f2b(n1 * cv.y + sgn * o1 * sv.y),
        f2b(n2 * cv.z + sgn * o2 * sv.z), f2b(n3 * cv.w + sgn * o3 * sv.w));
}

// ---------------------------------------------------------------------------
// K3: sliding-window flash attention, 16x16x32 MFMA.
// Block = 4 waves = 4 heads x same 16 queries (NKV=1: K/V staged once).
// K/V register-prefetched across the barrier (loads overlap MFMA phase).
// Fixed-max softmax (softcap bounds |s|<=50). P -> per-wave LDS -> B-operand
// of O^T = V^T P^T. 16x16 C/D: col=lane&15, row=(lane>>4)*4+reg.
// ---------------------------------------------------------------------------
__global__ __launch_bounds__(256, 2) void attn_mfma(
    const u16* __restrict__ Qb, const u16* __restrict__ Kb,
    const u16* __restrict__ Vtg, u16* __restrict__ AO)
{
    const int q0 = blockIdx.x * 16;
    const int b  = blockIdx.y;
    const int t = threadIdx.x, h = t >> 6, lane = t & 63;
    const int l15 = lane & 15, quad = lane >> 4;

    __shared__ __align__(16) u16 Ks[32][264];
    __shared__ __align__(16) u16 Vt[256][40];
    __shared__ __align__(16) u16 Pr[4][16][40];
    __shared__ float l_s[4][16];

    // Q A-fragments: lane: q = q0+l15, d = quad*8 + s*32 + j
    bf16x8 qf[8];
    {
        const u16* qp = Qb + ((size_t)(b * 4096 + q0 + l15)) * 1024 + h * 256 + quad * 8;
#pragma unroll
        for (int s = 0; s < 8; s++) qf[s] = *(const bf16x8*)(qp + s * 32);
    }

    f32x4 o[16];
#pragma unroll
    for (int i = 0; i < 16; i++) o[i] = (f32x4)0.0f;
    float lp[4] = {0.f, 0.f, 0.f, 0.f};

    const int lo = q0 - 511;
    const int jb0 = lo > 0 ? (lo >> 5) << 5 : 0;
    const int jb1 = (q0 + 15) & ~31;

    const u16* kbase = Kb + (size_t)b * 4096 * 256;
    const u16* vbase = Vtg + (size_t)b * 1048576;

    uint4 kreg[4], vreg[4];
#pragma unroll
    for (int i = 0; i < 4; i++) {
        int ci = t + 256 * i;
        kreg[i] = *(const uint4*)(kbase + (size_t)(jb0 + (ci >> 5)) * 256 + (ci & 31) * 8);
        vreg[i] = *(const uint4*)(vbase + (size_t)(ci >> 2) * 4096 + jb0 + (ci & 3) * 8);
    }

    for (int jb = jb0; jb <= jb1; jb += 32) {
        __syncthreads();
#pragma unroll
        for (int i = 0; i < 4; i++) {
            int ci = t + 256 * i;
            *(uint4*)&Ks[ci >> 5][(ci & 31) * 8] = kreg[i];
            *(uint4*)&Vt[ci >> 2][(ci & 3) * 8]  = vreg[i];
        }
        __syncthreads();
        if (jb + 32 <= jb1) {
            const int jn = jb + 32;
#pragma unroll
            for (int i = 0; i < 4; i++) {
                int ci = t + 256 * i;
                kreg[i] = *(const uint4*)(kbase + (size_t)(jn + (ci >> 5)) * 256 + (ci & 31) * 8);
                vreg[i] = *(const uint4*)(vbase + (size_t)(ci >> 2) * 4096 + jn + (ci & 3) * 8);
            }
        }

        // ---- S = Q K^T : 16 queries x 32 keys
        f32x4 s0 = (f32x4)0.0f, s1 = (f32x4)0.0f;
#pragma unroll
        for (int ds = 0; ds < 8; ds++) {
            bf16x8 kf0 = *(const bf16x8*)&Ks[l15][ds * 32 + quad * 8];
            bf16x8 kf1 = *(const bf16x8*)&Ks[16 + l15][ds * 32 + quad * 8];
            s0 = __builtin_amdgcn_mfma_f32_16x16x32_bf16(qf[ds], kf0, s0, 0, 0, 0);
            s1 = __builtin_amdgcn_mfma_f32_16x16x32_bf16(qf[ds], kf1, s1, 0, 0, 0);
        }
        // ---- softcap + mask + exp (fixed max), P -> LDS
        const int j0 = jb + l15;
#pragma unroll
        for (int r = 0; r < 4; r++) {
            int qi = q0 + quad * 4 + r;
            float p0 = __expf(capmask(s0[r], qi, j0));
            float p1 = __expf(capmask(s1[r], qi, j0 + 16));
            u16 pb0 = f2b(p0), pb1 = f2b(p1);
            Pr[h][quad * 4 + r][l15]      = pb0;
            Pr[h][quad * 4 + r][16 + l15] = pb1;
            lp[r] += b2f(pb0) + b2f(pb1);
        }
        __threadfence_block();
        // ---- O^T += V^T P^T
#pragma unroll
        for (int mt = 0; mt < 16; mt++) {
            bf16x8 vf = *(const bf16x8*)&Vt[mt * 16 + l15][quad * 8];
            bf16x8 pf = *(const bf16x8*)&Pr[h][l15][quad * 8];
            o[mt] = __builtin_amdgcn_mfma_f32_16x16x32_bf16(vf, pf, o[mt], 0, 0, 0);
        }
    }

    // ---- l reduction across the 16 key-lanes
#pragma unroll
    for (int r = 0; r < 4; r++) {
        float v = lp[r];
        v += __shfl_xor(v, 1, 64); v += __shfl_xor(v, 2, 64);
        v += __shfl_xor(v, 4, 64); v += __shfl_xor(v, 8, 64);
        lp[r] = v;
    }
    if (l15 == 0) {
#pragma unroll
        for (int r = 0; r < 4; r++) l_s[h][quad * 4 + r] = lp[r];
    }
    __threadfence_block();
    __syncthreads();
    const float inv = 1.0f / l_s[h][l15];

    u16* aop = AO + ((size_t)(b * 4096 + q0 + l15)) * 1024 + h * 256 + quad * 4;
#pragma unroll
    for (int mt = 0; mt < 16; mt++) {
        *(ushort4*)(aop + mt * 16) = make_ushort4(
            f2b(o[mt][0] * inv), f2b(o[mt][1] * inv),
            f2b(o[mt][2] * inv), f2b(o[mt][3] * inv));
    }
}

// ---------------------------------------------------------------------------
// K4: output projection (MFMA bf16 + global_load_lds staging).
// BM=128, BN=64 -> grid (10,64)=640 blocks. 4 waves 2x2 of 64x32.
// Epilogue via LDS tile -> coalesced float4/uint4 stores.
// ---------------------------------------------------------------------------
__global__ __launch_bounds__(256) void out_gemm(
    const u16* __restrict__ AO, const u16* __restrict__ WoT,
    const void* __restrict__ cosT, void* __restrict__ outp)
{
    const bool isbf = detect_bf16(cosT);
    const int n0 = blockIdx.x * 64, m0 = blockIdx.y * 128;
    const int t = threadIdx.x, w = t >> 6, lane = t & 63;
    const int l15 = lane & 15, quad = lane >> 4;
    const int wm = (w & 1) * 64, wn = (w >> 1) * 32;

    __shared__ __align__(16) u16 Ah[128][32];
    __shared__ __align__(16) u16 Bh[64][32];
    __shared__ __align__(16) float Scf[128][68];

    f32x4 acc[4][2];
#pragma unroll
    for (int i = 0; i < 4; i++)
#pragma unroll
        for (int j = 0; j < 2; j++) acc[i][j] = (f32x4)0.0f;

    for (int kb = 0; kb < 1024; kb += 32) {
        __syncthreads();
#pragma unroll
        for (int i = 0; i < 2; i++) {
            int ci = t + 256 * i, m = ci >> 2, c = ci & 3;
            gll16(AO + (size_t)(m0 + m) * 1024 + kb + c * 8, (char*)&Ah[0][0] + ci * 16);
        }
        {
            int m = t >> 2, c = t & 3;
            gll16(WoT + (size_t)(n0 + m) * 1024 + kb + c * 8, (char*)&Bh[0][0] + t * 16);
        }
        __syncthreads();
        bf16x8 af[4], bfr[2];
#pragma unroll
        for (int mi = 0; mi < 4; mi++)
            af[mi] = *(const bf16x8*)&Ah[wm + mi * 16 + l15][quad * 8];
#pragma unroll
        for (int ni = 0; ni < 2; ni++)
            bfr[ni] = *(const bf16x8*)&Bh[wn + ni * 16 + l15][quad * 8];
#pragma unroll
        for (int mi = 0; mi < 4; mi++)
#pragma unroll
            for (int ni = 0; ni < 2; ni++)
                acc[mi][ni] = __builtin_amdgcn_mfma_f32_16x16x32_bf16(
                    af[mi], bfr[ni], acc[mi][ni], 0, 0, 0);
    }

    __syncthreads();
#pragma unroll
    for (int mi = 0; mi < 4; mi++)
#pragma unroll
        for (int ni = 0; ni < 2; ni++)
#pragma unroll
            for (int r = 0; r < 4; r++)
                Scf[wm + mi * 16 + quad * 4 + r][wn + ni * 16 + l15] = acc[mi][ni][r];
    __syncthreads();

    if (isbf) {
#pragma unroll
        for (int i = 0; i < 4; i++) {
            int idx = t + 256 * i, r = idx >> 3, c = idx & 7;   // 128 rows x 8 chunks(8 cols)
            ushort4 lo4 = make_ushort4(
                f2b(Scf[r][c * 8 + 0]), f2b(Scf[r][c * 8 + 1]),
                f2b(Scf[r][c * 8 + 2]), f2b(Scf[r][c * 8 + 3]));
            ushort4 hi4 = make_ushort4(
                f2b(Scf[r][c * 8 + 4]), f2b(Scf[r][c * 8 + 5]),
                f2b(Scf[r][c * 8 + 6]), f2b(Scf[r][c * 8 + 7]));
            u16* p = (u16*)outp + (size_t)(m0 + r) * 640 + n0 + c * 8;
            *(ushort4*)p = lo4; *(ushort4*)(p + 4) = hi4;
        }
    } else {
#pragma unroll
        for (int i = 0; i < 8; i++) {
            int idx = t + 256 * i, r = idx >> 4, c = idx & 15;  // 128 rows x 16 chunks(4 cols)
            float4 v = *(const float4*)&Scf[r][c * 4];
            *(float4*)((float*)outp + (size_t)(m0 + r) * 640 + n0 + c * 4) = v;
        }
    }
}

// ---------------------------------------------------------------------------
// Launch. Inputs: 0 hidden, 1 cos, 2 sin, 3 mask(UNUSED), 4 Wq, 5 Wk, 6 Wv,
// 7 Wo, 8 q_norm_w, 9 k_norm_w. Workspace (43.3 MB, AO overlays Hb+WT):
//   [0, 16.78M): Hb(10.49M) + WT(1.97M)  -- dead after GEMMs; AO reuses @0
//   [16.78M): WoT 1.31M | Qb 16.78M | Kb 4.19M | Vt_g 4.19M
// ---------------------------------------------------------------------------
extern "C" void kernel_launch(void* const* d_in, const int* in_sizes, int n_in,
                              void* d_out, int out_size, void* d_ws, size_t ws_size,
                              hipStream_t stream) {
    const void* hidden = d_in[0];
    const void* cosT   = d_in[1];
    const void* sinT   = d_in[2];
    const void* Wq     = d_in[4];
    const void* Wk     = d_in[5];
    const void* Wv     = d_in[6];
    const void* Wo     = d_in[7];
    const void* qw     = d_in[8];
    const void* kw     = d_in[9];

    char* ws = (char*)d_ws;
    u16* Hb  = (u16*)ws;                            // 8192*640
    u16* WT  = (u16*)(ws + 10485760);               // 1536*640
    u16* AO  = (u16*)ws;                            // 8192*1024 (overlays Hb/WT)
    u16* WoT = (u16*)(ws + 16777216);               // 640*1024
    u16* Qb  = (u16*)(ws + 18087936);               // 8192*1024
    u16* Kb  = (u16*)(ws + 34865152);               // 8192*256
    u16* Vtg = (u16*)(ws + 39059456);               // 2*256*4096

    prep<<<dim3(4160), 256, 0, stream>>>(hidden, Wq, Wk, Wv, Wo, cosT, Hb, WT, WoT);
    qkv_gemm<<<dim3(12, 64), 256, 0, stream>>>(Hb, WT, Qb, Kb, Vtg);
    norm_rope<<<dim3(8192), 320, 0, stream>>>(Qb, Kb, cosT, sinT, qw, kw);
    attn_mfma<<<dim3(256, 2), 256, 0, stream>>>(Qb, Kb, Vtg, AO);
    out_gemm<<<dim3(10, 64), 256, 0, stream>>>(AO, WoT, cosT, d_out);
}

// Round 7
// 331.835 us; speedup vs baseline: 1.2579x; 1.2079x over previous
//
#include <hip/hip_runtime.h>

typedef unsigned short u16;
typedef unsigned int u32;

typedef __attribute__((ext_vector_type(8)))  short bf16x8;
typedef __attribute__((ext_vector_type(4)))  float f32x4;

__device__ __forceinline__ float b2f(u16 u) {
    union { unsigned int i; float f; } v; v.i = ((unsigned int)u) << 16; return v.f;
}
__device__ __forceinline__ u16 f2b(float f) {
    union { float ff; unsigned int i; } v; v.ff = f;
    unsigned int x = v.i;
    return (u16)((x + 0x7fffu + ((x >> 16) & 1u)) >> 16);
}
__device__ __forceinline__ bool detect_bf16(const void* cosT) {
    // cos row 0 is all 1.0: fp32 word = 0x3F800000, bf16 pair = 0x3F803F80
    return ((*(const u32*)cosT) & 0xffffu) == 0x3f80u;
}
__device__ __forceinline__ float4 ld4(const void* p, size_t off, bool isbf) {
    if (isbf) {
        ushort4 v = *(const ushort4*)((const u16*)p + off);
        return make_float4(b2f(v.x), b2f(v.y), b2f(v.z), b2f(v.w));
    }
    return *(const float4*)((const float*)p + off);
}
__device__ __forceinline__ float lds1(const void* p, size_t off, bool isbf) {
    return isbf ? b2f(((const u16*)p)[off]) : ((const float*)p)[off];
}
// async 16B global -> LDS (dest = wave-uniform base + lane*16)
__device__ __forceinline__ void gll16(const void* g, void* l) {
    __builtin_amdgcn_global_load_lds(
        (const __attribute__((address_space(1))) u32*)g,
        (__attribute__((address_space(3))) u32*)l, 16, 0, 0);
}
// softcap + sliding-window mask. SCALING = 1/16, SOFTCAP = 50.
// masked -> -1e30, expf(-1e30) underflows to exactly 0.
__device__ __forceinline__ float capmask(float sdot, int i, int j) {
    float v = sdot * (0.0625f / 50.0f);
    v = fminf(fmaxf(v, -10.0f), 10.0f);
    float e = __expf(2.0f * v);
    float c = 50.0f * (e - 1.0f) / (e + 1.0f);
    bool allowed = (j <= i) && (j > i - 512);
    return allowed ? c : -1e30f;
}

// ---------------------------------------------------------------------------
// K0: prep = conv_hidden (blocks 0..2559) + weight transposes (2560..4159).
//   Hb[8192][640] bf16; WT[1536][640]; WoT[640][1024]
// ---------------------------------------------------------------------------
__global__ __launch_bounds__(256) void prep(
    const void* __restrict__ hidden,
    const void* __restrict__ Wq, const void* __restrict__ Wk,
    const void* __restrict__ Wv, const void* __restrict__ Wo,
    const void* __restrict__ cosT,
    u16* __restrict__ Hb, u16* __restrict__ WT, u16* __restrict__ WoT)
{
    const bool isbf = detect_bf16(cosT);
    __shared__ float T[32][33];
    int id = blockIdx.x;
    if (id < 2560) {
        size_t base = ((size_t)id * 256 + threadIdx.x) * 8;
        if (isbf) {
            *(uint4*)(Hb + base) = *(const uint4*)((const u16*)hidden + base);
        } else {
            float4 a = ld4(hidden, base, false);
            float4 b = ld4(hidden, base + 4, false);
            uint4 o;
            o.x = (u32)f2b(a.x) | ((u32)f2b(a.y) << 16);
            o.y = (u32)f2b(a.z) | ((u32)f2b(a.w) << 16);
            o.z = (u32)f2b(b.x) | ((u32)f2b(b.y) << 16);
            o.w = (u32)f2b(b.z) | ((u32)f2b(b.w) << 16);
            *(uint4*)(Hb + base) = o;
        }
        return;
    }
    id -= 2560;
    const int tx = threadIdx.x & 31, ty = threadIdx.x >> 5;
    if (id < 960) {
        const int n0 = (id % 48) * 32, k0 = (id / 48) * 32;
        const void* src; int ldw, nof;
        if (n0 < 1024)      { src = Wq; ldw = 1024; nof = n0; }
        else if (n0 < 1280) { src = Wk; ldw = 256;  nof = n0 - 1024; }
        else                { src = Wv; ldw = 256;  nof = n0 - 1280; }
#pragma unroll
        for (int j = 0; j < 4; j++)
            T[ty + 8 * j][tx] = lds1(src, (size_t)(k0 + ty + 8 * j) * ldw + nof + tx, isbf);
        __syncthreads();
#pragma unroll
        for (int j = 0; j < 4; j++)
            WT[(size_t)(n0 + ty + 8 * j) * 640 + k0 + tx] = f2b(T[tx][ty + 8 * j]);
    } else {
        id -= 960;
        const int k0 = (id & 31) * 32, n0 = (id >> 5) * 32;
#pragma unroll
        for (int j = 0; j < 4; j++)
            T[ty + 8 * j][tx] = lds1(Wo, (size_t)(k0 + ty + 8 * j) * 640 + n0 + tx, isbf);
        __syncthreads();
#pragma unroll
        for (int j = 0; j < 4; j++)
            WoT[(size_t)(n0 + ty + 8 * j) * 1024 + k0 + tx] = f2b(T[tx][ty + 8 * j]);
    }
}

// ---------------------------------------------------------------------------
// K1: QKV GEMM (MFMA bf16 + global_load_lds staging).
// 128x128 tile, BK=32, 4 waves (2x2 of 64x64), 16x16x32 MFMA.
// Epilogue: Q/K via LDS tile -> coalesced uint4 stores; V direct transposed.
// ---------------------------------------------------------------------------
__global__ __launch_bounds__(256) void qkv_gemm(
    const u16* __restrict__ Hb, const u16* __restrict__ WT,
    u16* __restrict__ Qb, u16* __restrict__ Kb, u16* __restrict__ Vtg)
{
    const int n0 = blockIdx.x * 128, m0 = blockIdx.y * 128;
    const int t = threadIdx.x, w = t >> 6, lane = t & 63;
    const int l15 = lane & 15, quad = lane >> 4;
    const int wm = (w & 1) * 64, wn = (w >> 1) * 64;

    __shared__ __align__(16) u16 Ah[128][32];
    __shared__ __align__(16) u16 Bh[128][32];
    __shared__ __align__(16) u16 Sc[128][132];

    f32x4 acc[4][4];
#pragma unroll
    for (int i = 0; i < 4; i++)
#pragma unroll
        for (int j = 0; j < 4; j++) acc[i][j] = (f32x4)0.0f;

    for (int kb = 0; kb < 640; kb += 32) {
        __syncthreads();
#pragma unroll
        for (int i = 0; i < 2; i++) {
            int ci = t + 256 * i, m = ci >> 2, c = ci & 3;
            gll16(Hb + (size_t)(m0 + m) * 640 + kb + c * 8, (char*)&Ah[0][0] + ci * 16);
            gll16(WT + (size_t)(n0 + m) * 640 + kb + c * 8, (char*)&Bh[0][0] + ci * 16);
        }
        __syncthreads();
        bf16x8 af[4], bfr[4];
#pragma unroll
        for (int mi = 0; mi < 4; mi++)
            af[mi] = *(const bf16x8*)&Ah[wm + mi * 16 + l15][quad * 8];
#pragma unroll
        for (int ni = 0; ni < 4; ni++)
            bfr[ni] = *(const bf16x8*)&Bh[wn + ni * 16 + l15][quad * 8];
#pragma unroll
        for (int mi = 0; mi < 4; mi++)
#pragma unroll
            for (int ni = 0; ni < 4; ni++)
                acc[mi][ni] = __builtin_amdgcn_mfma_f32_16x16x32_bf16(
                    af[mi], bfr[ni], acc[mi][ni], 0, 0, 0);
    }

    if (n0 >= 1280) {
        // V region: direct transposed store (already vectorized)
        const int bb = m0 >> 12, sblk = m0 & 4095;
#pragma unroll
        for (int mi = 0; mi < 4; mi++)
#pragma unroll
            for (int ni = 0; ni < 4; ni++) {
                int vd = n0 + wn + ni * 16 + l15 - 1280;
                int sb = sblk + wm + mi * 16 + quad * 4;
                ushort4 vv = make_ushort4(f2b(acc[mi][ni][0]), f2b(acc[mi][ni][1]),
                                          f2b(acc[mi][ni][2]), f2b(acc[mi][ni][3]));
                *(ushort4*)(Vtg + (size_t)bb * 1048576 + (size_t)vd * 4096 + sb) = vv;
            }
        return;
    }

    __syncthreads();   // LDS tiles dead; reuse Sc
#pragma unroll
    for (int mi = 0; mi < 4; mi++)
#pragma unroll
        for (int ni = 0; ni < 4; ni++)
#pragma unroll
            for (int r = 0; r < 4; r++)
                Sc[wm + mi * 16 + quad * 4 + r][wn + ni * 16 + l15] = f2b(acc[mi][ni][r]);
    __syncthreads();

    u16* dst; int ldo, coff;
    if (n0 < 1024) { dst = Qb; ldo = 1024; coff = n0; }
    else           { dst = Kb; ldo = 256;  coff = n0 - 1024; }
#pragma unroll
    for (int i = 0; i < 8; i++) {
        int idx = t + 256 * i, r = idx >> 4, c = idx & 15;
        *(uint4*)(dst + (size_t)(m0 + r) * ldo + coff + c * 8) = *(const uint4*)&Sc[r][c * 8];
    }
}

// ---------------------------------------------------------------------------
// K2: fused RMS-norm + RoPE in place on Qb (4 heads) and Kb (1 head).
// ---------------------------------------------------------------------------
__global__ __launch_bounds__(320) void norm_rope(
    u16* __restrict__ Qb, u16* __restrict__ Kb,
    const void* __restrict__ cosT, const void* __restrict__ sinT,
    const void* __restrict__ qw, const void* __restrict__ kw)
{
    const bool isbf = detect_bf16(cosT);
    const int row = blockIdx.x, s = row & 4095;
    const int g = threadIdx.x >> 6, lane = threadIdx.x & 63, d0 = lane * 4;

    u16* p; const void* w;
    if (g < 4) { p = Qb + (size_t)row * 1024 + g * 256 + d0; w = qw; }
    else       { p = Kb + (size_t)row * 256 + d0;            w = kw; }

    ushort4 xv = *(const ushort4*)p;
    float x0 = b2f(xv.x), x1 = b2f(xv.y), x2 = b2f(xv.z), x3 = b2f(xv.w);
    float ssum = x0 * x0 + x1 * x1 + x2 * x2 + x3 * x3;
#pragma unroll
    for (int off = 32; off > 0; off >>= 1) ssum += __shfl_xor(ssum, off, 64);
    float rs = rsqrtf(ssum * (1.0f / 256.0f) + 1e-6f);

    float4 wv = ld4(w, d0, isbf);
    float n0 = x0 * rs * (1.0f + wv.x);
    float n1 = x1 * rs * (1.0f + wv.y);
    float n2 = x2 * rs * (1.0f + wv.z);
    float n3 = x3 * rs * (1.0f + wv.w);

    float o0 = __shfl_xor(n0, 32, 64);
    float o1 = __shfl_xor(n1, 32, 64);
    float o2 = __shfl_xor(n2, 32, 64);
    float o3 = __shfl_xor(n3, 32, 64);
    float sgn = (lane < 32) ? -1.0f : 1.0f;

    float4 cv = ld4(cosT, (size_t)s * 256 + d0, isbf);
    float4 sv = ld4(sinT, (size_t)s * 256 + d0, isbf);
    *(ushort4*)p = make_ushort4(
        f2b(n0 * cv.x + sgn * o0 * sv.x), f2b(n1 * cv.y + sgn * o1 * sv.y),
        f2b(n2 * cv.z + sgn * o2 * sv.z), f2b(n3 * cv.w + sgn * o3 * sv.w));
}

// ---------------------------------------------------------------------------
// K3: sliding-window flash attention, 16x16x32 MFMA.
// Block = 4 waves = 4 heads x same 16 queries (NKV=1: K/V staged once).
// Direct load->LDS staging (NO cross-barrier register prefetch: the compiler
// spills it to scratch -- rounds 5/6 showed 260+ MB scratch WRITE_SIZE).
// XCD-aware swizzle: q-tile = (bx&7)*32 + (bx>>3) gives each XCD a
// contiguous 512-query span -> K/V working set ~2 MB fits per-XCD L2.
// Fixed-max softmax (softcap bounds |s|<=50). P -> per-wave LDS -> B-operand
// of O^T = V^T P^T. 16x16 C/D: col=lane&15, row=(lane>>4)*4+reg.
// ---------------------------------------------------------------------------
__global__ __launch_bounds__(256, 2) void attn_mfma(
    const u16* __restrict__ Qb, const u16* __restrict__ Kb,
    const u16* __restrict__ Vtg, u16* __restrict__ AO)
{
    const int bx = blockIdx.x;
    const int q0 = (((bx & 7) << 5) + (bx >> 3)) * 16;
    const int b  = blockIdx.y;
    const int t = threadIdx.x, h = t >> 6, lane = t & 63;
    const int l15 = lane & 15, quad = lane >> 4;

    __shared__ __align__(16) u16 Ks[32][264];
    __shared__ __align__(16) u16 Vt[256][40];
    __shared__ __align__(16) u16 Pr[4][16][40];
    __shared__ float l_s[4][16];

    // Q A-fragments: lane: q = q0+l15, d = quad*8 + s*32 + j
    bf16x8 qf[8];
    {
        const u16* qp = Qb + ((size_t)(b * 4096 + q0 + l15)) * 1024 + h * 256 + quad * 8;
#pragma unroll
        for (int s = 0; s < 8; s++) qf[s] = *(const bf16x8*)(qp + s * 32);
    }

    f32x4 o[16];
#pragma unroll
    for (int i = 0; i < 16; i++) o[i] = (f32x4)0.0f;
    float lp[4] = {0.f, 0.f, 0.f, 0.f};

    const int lo = q0 - 511;
    const int jb0 = lo > 0 ? (lo >> 5) << 5 : 0;
    const int jb1 = (q0 + 15) & ~31;

    const u16* kbase = Kb + (size_t)b * 4096 * 256;
    const u16* vbase = Vtg + (size_t)b * 1048576;

    for (int jb = jb0; jb <= jb1; jb += 32) {
        __syncthreads();
        // stage K [32 keys][256 d] and Vt [256 d][32 keys], shared by 4 heads
#pragma unroll
        for (int i = 0; i < 4; i++) {
            int ci = t + 256 * i;
            *(uint4*)&Ks[ci >> 5][(ci & 31) * 8] =
                *(const uint4*)(kbase + (size_t)(jb + (ci >> 5)) * 256 + (ci & 31) * 8);
            *(uint4*)&Vt[ci >> 2][(ci & 3) * 8] =
                *(const uint4*)(vbase + (size_t)(ci >> 2) * 4096 + jb + (ci & 3) * 8);
        }
        __syncthreads();

        // ---- S = Q K^T : 16 queries x 32 keys
        f32x4 s0 = (f32x4)0.0f, s1 = (f32x4)0.0f;
#pragma unroll
        for (int ds = 0; ds < 8; ds++) {
            bf16x8 kf0 = *(const bf16x8*)&Ks[l15][ds * 32 + quad * 8];
            bf16x8 kf1 = *(const bf16x8*)&Ks[16 + l15][ds * 32 + quad * 8];
            s0 = __builtin_amdgcn_mfma_f32_16x16x32_bf16(qf[ds], kf0, s0, 0, 0, 0);
            s1 = __builtin_amdgcn_mfma_f32_16x16x32_bf16(qf[ds], kf1, s1, 0, 0, 0);
        }
        // ---- softcap + mask + exp (fixed max), P -> LDS
        const int j0 = jb + l15;
#pragma unroll
        for (int r = 0; r < 4; r++) {
            int qi = q0 + quad * 4 + r;
            float p0 = __expf(capmask(s0[r], qi, j0));
            float p1 = __expf(capmask(s1[r], qi, j0 + 16));
            u16 pb0 = f2b(p0), pb1 = f2b(p1);
            Pr[h][quad * 4 + r][l15]      = pb0;
            Pr[h][quad * 4 + r][16 + l15] = pb1;
            lp[r] += b2f(pb0) + b2f(pb1);
        }
        __threadfence_block();
        // ---- O^T += V^T P^T
        bf16x8 pf = *(const bf16x8*)&Pr[h][l15][quad * 8];
#pragma unroll
        for (int mt = 0; mt < 16; mt++) {
            bf16x8 vf = *(const bf16x8*)&Vt[mt * 16 + l15][quad * 8];
            o[mt] = __builtin_amdgcn_mfma_f32_16x16x32_bf16(vf, pf, o[mt], 0, 0, 0);
        }
    }

    // ---- l reduction across the 16 key-lanes
#pragma unroll
    for (int r = 0; r < 4; r++) {
        float v = lp[r];
        v += __shfl_xor(v, 1, 64); v += __shfl_xor(v, 2, 64);
        v += __shfl_xor(v, 4, 64); v += __shfl_xor(v, 8, 64);
        lp[r] = v;
    }
    if (l15 == 0) {
#pragma unroll
        for (int r = 0; r < 4; r++) l_s[h][quad * 4 + r] = lp[r];
    }
    __threadfence_block();
    __syncthreads();
    const float inv = 1.0f / l_s[h][l15];

    u16* aop = AO + ((size_t)(b * 4096 + q0 + l15)) * 1024 + h * 256 + quad * 4;
#pragma unroll
    for (int mt = 0; mt < 16; mt++) {
        *(ushort4*)(aop + mt * 16) = make_ushort4(
            f2b(o[mt][0] * inv), f2b(o[mt][1] * inv),
            f2b(o[mt][2] * inv), f2b(o[mt][3] * inv));
    }
}

// ---------------------------------------------------------------------------
// K4: output projection (MFMA bf16 + global_load_lds staging).
// BM=128, BN=64 -> grid (10,64)=640 blocks. 4 waves 2x2 of 64x32.
// Epilogue via LDS tile -> coalesced float4/uint4 stores.
// ---------------------------------------------------------------------------
__global__ __launch_bounds__(256) void out_gemm(
    const u16* __restrict__ AO, const u16* __restrict__ WoT,
    const void* __restrict__ cosT, void* __restrict__ outp)
{
    const bool isbf = detect_bf16(cosT);
    const int n0 = blockIdx.x * 64, m0 = blockIdx.y * 128;
    const int t = threadIdx.x, w = t >> 6, lane = t & 63;
    const int l15 = lane & 15, quad = lane >> 4;
    const int wm = (w & 1) * 64, wn = (w >> 1) * 32;

    __shared__ __align__(16) u16 Ah[128][32];
    __shared__ __align__(16) u16 Bh[64][32];
    __shared__ __align__(16) float Scf[128][68];

    f32x4 acc[4][2];
#pragma unroll
    for (int i = 0; i < 4; i++)
#pragma unroll
        for (int j = 0; j < 2; j++) acc[i][j] = (f32x4)0.0f;

    for (int kb = 0; kb < 1024; kb += 32) {
        __syncthreads();
#pragma unroll
        for (int i = 0; i < 2; i++) {
            int ci = t + 256 * i, m = ci >> 2, c = ci & 3;
            gll16(AO + (size_t)(m0 + m) * 1024 + kb + c * 8, (char*)&Ah[0][0] + ci * 16);
        }
        {
            int m = t >> 2, c = t & 3;
            gll16(WoT + (size_t)(n0 + m) * 1024 + kb + c * 8, (char*)&Bh[0][0] + t * 16);
        }
        __syncthreads();
        bf16x8 af[4], bfr[2];
#pragma unroll
        for (int mi = 0; mi < 4; mi++)
            af[mi] = *(const bf16x8*)&Ah[wm + mi * 16 + l15][quad * 8];
#pragma unroll
        for (int ni = 0; ni < 2; ni++)
            bfr[ni] = *(const bf16x8*)&Bh[wn + ni * 16 + l15][quad * 8];
#pragma unroll
        for (int mi = 0; mi < 4; mi++)
#pragma unroll
            for (int ni = 0; ni < 2; ni++)
                acc[mi][ni] = __builtin_amdgcn_mfma_f32_16x16x32_bf16(
                    af[mi], bfr[ni], acc[mi][ni], 0, 0, 0);
    }

    __syncthreads();
#pragma unroll
    for (int mi = 0; mi < 4; mi++)
#pragma unroll
        for (int ni = 0; ni < 2; ni++)
#pragma unroll
            for (int r = 0; r < 4; r++)
                Scf[wm + mi * 16 + quad * 4 + r][wn + ni * 16 + l15] = acc[mi][ni][r];
    __syncthreads();

    if (isbf) {
#pragma unroll
        for (int i = 0; i < 4; i++) {
            int idx = t + 256 * i, r = idx >> 3, c = idx & 7;   // 128 rows x 8 chunks(8 cols)
            ushort4 lo4 = make_ushort4(
                f2b(Scf[r][c * 8 + 0]), f2b(Scf[r][c * 8 + 1]),
                f2b(Scf[r][c * 8 + 2]), f2b(Scf[r][c * 8 + 3]));
            ushort4 hi4 = make_ushort4(
                f2b(Scf[r][c * 8 + 4]), f2b(Scf[r][c * 8 + 5]),
                f2b(Scf[r][c * 8 + 6]), f2b(Scf[r][c * 8 + 7]));
            u16* p = (u16*)outp + (size_t)(m0 + r) * 640 + n0 + c * 8;
            *(ushort4*)p = lo4; *(ushort4*)(p + 4) = hi4;
        }
    } else {
#pragma unroll
        for (int i = 0; i < 8; i++) {
            int idx = t + 256 * i, r = idx >> 4, c = idx & 15;  // 128 rows x 16 chunks(4 cols)
            float4 v = *(const float4*)&Scf[r][c * 4];
            *(float4*)((float*)outp + (size_t)(m0 + r) * 640 + n0 + c * 4) = v;
        }
    }
}

// ---------------------------------------------------------------------------
// Launch. Inputs: 0 hidden, 1 cos, 2 sin, 3 mask(UNUSED), 4 Wq, 5 Wk, 6 Wv,
// 7 Wo, 8 q_norm_w, 9 k_norm_w. Workspace (43.3 MB, AO overlays Hb+WT):
//   [0, 16.78M): Hb(10.49M) + WT(1.97M)  -- dead after GEMMs; AO reuses @0
//   [16.78M): WoT 1.31M | Qb 16.78M | Kb 4.19M | Vt_g 4.19M
// ---------------------------------------------------------------------------
extern "C" void kernel_launch(void* const* d_in, const int* in_sizes, int n_in,
                              void* d_out, int out_size, void* d_ws, size_t ws_size,
                              hipStream_t stream) {
    const void* hidden = d_in[0];
    const void* cosT   = d_in[1];
    const void* sinT   = d_in[2];
    const void* Wq     = d_in[4];
    const void* Wk     = d_in[5];
    const void* Wv     = d_in[6];
    const void* Wo     = d_in[7];
    const void* qw     = d_in[8];
    const void* kw     = d_in[9];

    char* ws = (char*)d_ws;
    u16* Hb  = (u16*)ws;                            // 8192*640
    u16* WT  = (u16*)(ws + 10485760);               // 1536*640
    u16* AO  = (u16*)ws;                            // 8192*1024 (overlays Hb/WT)
    u16* WoT = (u16*)(ws + 16777216);               // 640*1024
    u16* Qb  = (u16*)(ws + 18087936);               // 8192*1024
    u16* Kb  = (u16*)(ws + 34865152);               // 8192*256
    u16* Vtg = (u16*)(ws + 39059456);               // 2*256*4096

    prep<<<dim3(4160), 256, 0, stream>>>(hidden, Wq, Wk, Wv, Wo, cosT, Hb, WT, WoT);
    qkv_gemm<<<dim3(12, 64), 256, 0, stream>>>(Hb, WT, Qb, Kb, Vtg);
    norm_rope<<<dim3(8192), 320, 0, stream>>>(Qb, Kb, cosT, sinT, qw, kw);
    attn_mfma<<<dim3(256, 2), 256, 0, stream>>>(Qb, Kb, Vtg, AO);
    out_gemm<<<dim3(10, 64), 256, 0, stream>>>(AO, WoT, cosT, d_out);
}